// Round 16
// baseline (3858.359 us; speedup 1.0000x reference)
//
#include <hip/hip_runtime.h>

typedef unsigned short u16;
typedef unsigned int u32;
typedef float f32x4 __attribute__((ext_vector_type(4)));
typedef _Float16 f16x8 __attribute__((ext_vector_type(8)));

#define VOCAB 32000
#define EMBED 512
#define HIDDEN 1024
#define BATCH 64
#define SEQ 512
#define G4H 4096
#define LBLK 64  // lstm persistent blocks

// ---------- fp16 helpers ----------
static __device__ __forceinline__ float h2f(u16 v) {
  _Float16 h;
  __builtin_memcpy(&h, &v, 2);
  return (float)h;
}
static __device__ __forceinline__ u16 f2h(float f) {
  _Float16 h = (_Float16)f;
  u16 v;
  __builtin_memcpy(&v, &h, 2);
  return v;
}
static __device__ __forceinline__ u32 pk2h(float a, float b) {
  return (u32)f2h(a) | ((u32)f2h(b) << 16);
}
static __device__ __forceinline__ float sigmoidf_(float x) {
  return 1.f / (1.f + __expf(-x));
}
static __device__ __forceinline__ float tanhf_(float x) {
  return 1.f - 2.f / (__expf(2.f * x) + 1.f);
}
static __device__ __forceinline__ f16x8 cvt8(const float* p) {
  float4 a = *(const float4*)p, b = *(const float4*)(p + 4);
  f16x8 v;
  v[0] = (_Float16)a.x; v[1] = (_Float16)a.y;
  v[2] = (_Float16)a.z; v[3] = (_Float16)a.w;
  v[4] = (_Float16)b.x; v[5] = (_Float16)b.y;
  v[6] = (_Float16)b.z; v[7] = (_Float16)b.w;
  return v;
}
static __device__ __forceinline__ f16x8 cvt8r(float4 a, float4 b) {
  f16x8 v;
  v[0] = (_Float16)a.x; v[1] = (_Float16)a.y;
  v[2] = (_Float16)a.z; v[3] = (_Float16)a.w;
  v[4] = (_Float16)b.x; v[5] = (_Float16)b.y;
  v[6] = (_Float16)b.z; v[7] = (_Float16)b.w;
  return v;
}

// coherent (cross-XCD) 16B load: bypasses L1/L2, served by IF/L3
#define GLOADC(dst, addr)                                  \
  asm volatile("global_load_dwordx4 %0, %1, off sc0 sc1"  \
               : "=v"(dst)                                 \
               : "v"(addr)                                 \
               : "memory")

// =====================================================================
// Phase A: xp = emb_table[x] @ W_ih^T + b_ih + b_hh, fp16 MFMA GEMM.
// Output layout [t][b][u*4+c]. (R10 version — verified 3x)
// =====================================================================
__global__ __launch_bounds__(256, 2) void phaseA(
    const int* __restrict__ x, const float* __restrict__ emb,
    const float* __restrict__ Wih, const float* __restrict__ bih,
    const float* __restrict__ bhh, u16* __restrict__ xp) {
  __shared__ __align__(16) _Float16 Al[128 * 32];
  __shared__ __align__(16) _Float16 Bl[128 * 32];
  const int t = threadIdx.x;
  const int bx = blockIdx.x;  // n-tile 0..31
  const int by = blockIdx.y;  // m-tile 0..255
  const int m0 = by * 128;
  const int u0 = bx * 32;

  const int r0 = x[m0 + (t >> 2)];
  const int r1 = x[m0 + 64 + (t >> 2)];
  const int nl0 = t >> 2, nl1 = 64 + (t >> 2);
  const int wrow0 = u0 + (nl0 >> 2) + (nl0 & 3) * 1024;
  const int wrow1 = u0 + (nl1 >> 2) + (nl1 & 3) * 1024;
  const int kq = t & 3;
  const float* pA0 = emb + (size_t)r0 * EMBED + kq * 8;
  const float* pA1 = emb + (size_t)r1 * EMBED + kq * 8;
  const float* pB0 = Wih + (size_t)wrow0 * EMBED + kq * 8;
  const float* pB1 = Wih + (size_t)wrow1 * EMBED + kq * 8;

  const int wid = t >> 6, l = t & 63;
  const int wr = wid >> 1, wc = wid & 1;
  const int lm = l & 15, lk = l >> 4;

  f32x4 acc[4][4];
#pragma unroll
  for (int i = 0; i < 4; ++i)
#pragma unroll
    for (int j = 0; j < 4; ++j) acc[i][j] = (f32x4){0.f, 0.f, 0.f, 0.f};

  // preload K-chunk 0 into named registers
  float4 ra0a = *(const float4*)(pA0), ra0b = *(const float4*)(pA0 + 4);
  float4 ra1a = *(const float4*)(pA1), ra1b = *(const float4*)(pA1 + 4);
  float4 rb0a = *(const float4*)(pB0), rb0b = *(const float4*)(pB0 + 4);
  float4 rb1a = *(const float4*)(pB1), rb1b = *(const float4*)(pB1 + 4);

  for (int k0 = 0; k0 < EMBED; k0 += 32) {
    *(f16x8*)(Al + t * 8) = cvt8r(ra0a, ra0b);
    *(f16x8*)(Al + (t + 256) * 8) = cvt8r(ra1a, ra1b);
    *(f16x8*)(Bl + t * 8) = cvt8r(rb0a, rb0b);
    *(f16x8*)(Bl + (t + 256) * 8) = cvt8r(rb1a, rb1b);
    __syncthreads();
    if (k0 + 32 < EMBED) {  // issue next chunk early; retires during MFMAs
      const int kn = k0 + 32;
      ra0a = *(const float4*)(pA0 + kn); ra0b = *(const float4*)(pA0 + kn + 4);
      ra1a = *(const float4*)(pA1 + kn); ra1b = *(const float4*)(pA1 + kn + 4);
      rb0a = *(const float4*)(pB0 + kn); rb0b = *(const float4*)(pB0 + kn + 4);
      rb1a = *(const float4*)(pB1 + kn); rb1b = *(const float4*)(pB1 + kn + 4);
    }
    f16x8 af[4], bf[4];
#pragma unroll
    for (int mt = 0; mt < 4; ++mt)
      af[mt] = *(const f16x8*)(Al + (wr * 64 + mt * 16 + lm) * 32 + lk * 8);
#pragma unroll
    for (int nt = 0; nt < 4; ++nt)
      bf[nt] = *(const f16x8*)(Bl + (wc * 64 + nt * 16 + lm) * 32 + lk * 8);
#pragma unroll
    for (int mt = 0; mt < 4; ++mt)
#pragma unroll
      for (int nt = 0; nt < 4; ++nt)
        acc[mt][nt] = __builtin_amdgcn_mfma_f32_16x16x32_f16(
            af[mt], bf[nt], acc[mt][nt], 0, 0, 0);
    __syncthreads();
  }

#pragma unroll
  for (int nt = 0; nt < 4; ++nt) {
    const int nloc = wc * 64 + nt * 16 + lm;
    const int grow = u0 + (nloc >> 2) + (nloc & 3) * 1024;
    const float bsum = bih[grow] + bhh[grow];
#pragma unroll
    for (int mt = 0; mt < 4; ++mt)
#pragma unroll
      for (int r = 0; r < 4; ++r) {
        const int m = m0 + wr * 64 + mt * 16 + lk * 4 + r;
        const int bb = m >> 9, tt = m & 511;
        xp[((size_t)tt * 64 + bb) * G4H + bx * 128 + nloc] =
            f2h(acc[mt][nt][r] + bsum);
      }
  }
}

// =====================================================================
// Persistent LSTM, 64 blocks x 512 thr (8 waves), cooperative.
// R16 (vs R15): ps writes split b64 -> 2x b32 with extra ^((l&1)<<2).
// b64's dword pair always hits an (even,odd) bank pair -> .x dwords
// 4-way on 16 even banks (bank bit0 unreachable by XOR bits >=3).
// b32 + bit-2 XOR lets odd lanes swap x/y slots -> all 32 banks,
// 2 lanes/bank = free (m136). Reads decode with ^((gb&1)<<2);
// verified 2-way-free. Arithmetic bit-identical.
// =====================================================================
__global__ __launch_bounds__(512, 2) void lstm_steps(
    const u16* __restrict__ xp, const float* __restrict__ Whh,
    u16* __restrict__ hA, u16* __restrict__ hB, u16* __restrict__ hT,
    unsigned* __restrict__ flags) {
  __shared__ __align__(16) char psb[65536];
  const int t = threadIdx.x;
  const int blk = blockIdx.x;
  const int kw = t >> 6;  // wave id = K-slice
  const int l = t & 63;
  const int lm = l & 15, lk = l >> 4;

  // ---- W_hh A-frags (fp16), once: wf[rt=gate][kf] ----
  f16x8 wf[4][4];
#pragma unroll
  for (int rt = 0; rt < 4; ++rt)
#pragma unroll
    for (int kf = 0; kf < 4; ++kf)
      wf[rt][kf] = cvt8(Whh + (size_t)(rt * HIDDEN + blk * 16 + lm) * HIDDEN +
                        kw * 128 + kf * 32 + lk * 8);

  const int gb = t >> 3, gup = t & 7;  // gate-math role: batch, unit-pair
  // write bases: word x at (l*8)^sw, word y at (l*8+4)^sw,
  // sw = ((lk&1)<<6) | ((l&1)<<2)  -> odd lanes swap x/y slots
  const unsigned swz = (unsigned)(((lk & 1) << 6) | ((l & 1) << 2));
  const unsigned wx = (unsigned)(kw * 8192) + ((unsigned)(l * 8) ^ swz);
  const unsigned wy = (unsigned)(kw * 8192) + ((unsigned)(l * 8 + 4) ^ swz);
  // read: producer lane lp=(gup>>1)*16+(gb&15), word d=gup&1;
  // byte = (lp*8 + d*4) ^ ((lp>>4 &1)<<6) ^ ((lp&1)<<2); lp&1 == gb&1
  const unsigned roff =
      (unsigned)((gb >> 4) * 512 +
                 (((gup >> 1) * 128 + (gb & 15) * 8 + (gup & 1) * 4) ^
                  (((gup >> 1) & 1) << 6) ^ ((gb & 1) << 2)));
  const size_t xpofs = (size_t)gb * G4H + (size_t)blk * 64 + gup * 8;
  const int pfl = (kw * 8 + (l & 7)) * 32;  // producer-subset poll index
  float c0 = 0.f, c1 = 0.f;

  // prefetch xv for s=0 (retired by first bt-loop's waits)
  f16x8 xv;
  GLOADC(xv, xp + xpofs);

  for (int s = 0; s < SEQ; ++s) {
    const u16* hp = (s & 1) ? hB : hA;
    u16* hn = (s & 1) ? hA : hB;

    // 16 h loads (producers for this wave's k-slice already flagged)
    f16x8 bv[4][4];
#pragma unroll
    for (int bt = 0; bt < 4; ++bt)
#pragma unroll
      for (int kf = 0; kf < 4; ++kf)
        GLOADC(bv[bt][kf], hp + (size_t)(bt * 16 + lm) * HIDDEN + kw * 128 +
                               kf * 32 + lk * 8);

    f32x4 acc[4][4];
#pragma unroll
    for (int i = 0; i < 4; ++i)
#pragma unroll
      for (int j = 0; j < 4; ++j) acc[i][j] = (f32x4){0.f, 0.f, 0.f, 0.f};

#pragma unroll
    for (int bt = 0; bt < 4; ++bt) {
      if (bt == 0) asm volatile("s_waitcnt vmcnt(12)" ::: "memory");
      else if (bt == 1) asm volatile("s_waitcnt vmcnt(8)" ::: "memory");
      else if (bt == 2) asm volatile("s_waitcnt vmcnt(4)" ::: "memory");
      else asm volatile("s_waitcnt vmcnt(0)" ::: "memory");
      __builtin_amdgcn_sched_barrier(0);
#pragma unroll
      for (int rt = 0; rt < 4; ++rt)
#pragma unroll
        for (int kf = 0; kf < 4; ++kf)
          acc[rt][bt] = __builtin_amdgcn_mfma_f32_16x16x32_f16(
              wf[rt][kf], bv[bt][kf], acc[rt][bt], 0, 0, 0);
    }

    // ps writes: 32 x ds_write_b32, 2 lanes/bank = conflict-free
#pragma unroll
    for (int rt = 0; rt < 4; ++rt)
#pragma unroll
      for (int bt = 0; bt < 4; ++bt) {
        const unsigned so = (unsigned)((rt * 4 + bt) * 512);
        *(u32*)(psb + wx + so) = pk2h(acc[rt][bt][0], acc[rt][bt][1]);
        *(u32*)(psb + wy + so) = pk2h(acc[rt][bt][2], acc[rt][bt][3]);
      }
    __syncthreads();  // sync1: ps writes visible; all waves converged

    // ---- gate math: thread (gb, gup) -> units gup*2, gup*2+1 ----
    float s0[4], s1[4];
#pragma unroll
    for (int c = 0; c < 4; ++c) {
      s0[c] = (float)xv[c];
      s1[c] = (float)xv[4 + c];
    }
#pragma unroll
    for (int c = 0; c < 4; ++c)
#pragma unroll
      for (int k8 = 0; k8 < 8; ++k8) {
        const u32 pv = *(const u32*)(psb + k8 * 8192 + c * 2048 + roff);
        s0[c] += h2f((u16)(pv & 0xffffu));
        s1[c] += h2f((u16)(pv >> 16));
      }
    float go0, go1;
    {
      const float ig = sigmoidf_(s0[0]), fg = sigmoidf_(s0[1]);
      const float gv = tanhf_(s0[2]), og = sigmoidf_(s0[3]);
      c0 = fg * c0 + ig * gv;
      go0 = og * tanhf_(c0);
    }
    {
      const float ig = sigmoidf_(s1[0]), fg = sigmoidf_(s1[1]);
      const float gv = tanhf_(s1[2]), og = sigmoidf_(s1[3]);
      c1 = fg * c1 + ig * gv;
      go1 = og * tanhf_(c1);
    }

    if (s == SEQ - 1) {
      // final: write transposed hT[k][b] directly for phaseC
      hT[(size_t)(blk * 16 + gup * 2) * 64 + gb] = f2h(go0);
      hT[(size_t)(blk * 16 + gup * 2 + 1) * 64 + gb] = f2h(go1);
      break;
    }

    const unsigned hpack = (unsigned)f2h(go0) | ((unsigned)f2h(go1) << 16);
    __hip_atomic_store(
        (unsigned*)(hn + (size_t)gb * HIDDEN + blk * 16 + gup * 2), hpack,
        __ATOMIC_RELAXED, __HIP_MEMORY_SCOPE_AGENT);

    // prefetch next step's xp slice (gate math above already consumed xv);
    // issued AFTER the h store so vmcnt(1) drains the store, not this load
    GLOADC(xv, xp + (size_t)(s + 1) * (64 * G4H) + xpofs);
    asm volatile("s_waitcnt vmcnt(1)" ::: "memory");  // drain h store only
    __syncthreads();  // sync2: all waves' h stores drained; ps reads done
    if (t == 0)
      __hip_atomic_store(flags + blk * 32, (unsigned)(s + 1), __ATOMIC_RELAXED,
                         __HIP_MEMORY_SCOPE_AGENT);
    // all-wave producer-subset poll: wave kw waits on blocks kw*8..kw*8+7
    {
      const unsigned tgt = (unsigned)(s + 1);
      while (true) {
        unsigned v = __hip_atomic_load(flags + pfl, __ATOMIC_RELAXED,
                                       __HIP_MEMORY_SCOPE_AGENT);
        if (__all((int)(v >= tgt))) break;
        __builtin_amdgcn_s_sleep(1);
      }
    }
  }
}

// =====================================================================
// Phase C: out[b][v] = sum_k hT[k][b] * W_fc[v][k] + b_fc[v]
// R16: W_fc staging vectorized to float4 (memory-bound phase, G13).
// =====================================================================
__global__ __launch_bounds__(256) void phaseC(
    const u16* __restrict__ hT, const float* __restrict__ Wfc,
    const float* __restrict__ bfc, float* __restrict__ out) {
  __shared__ float Ws[32][129];
  __shared__ __align__(16) float hs[128][68];
  const int t = threadIdx.x;
  const int v0 = blockIdx.x * 32;
  const int lane = t & 63;
  const int w = t >> 6;
  const int v = lane & 31;
  const int bbase = ((w << 1) | (lane >> 5)) << 3;
  float acc[8] = {0.f, 0.f, 0.f, 0.f, 0.f, 0.f, 0.f, 0.f};

  for (int kc = 0; kc < HIDDEN; kc += 128) {
#pragma unroll
    for (int i = 0; i < 4; ++i) {
      int e = t + i * 256;          // 1024 float4 = 32 rows x 32 quads
      int vv = e >> 5, k4 = e & 31;
      float4 w4 = *(const float4*)&Wfc[(size_t)(v0 + vv) * HIDDEN + kc + k4 * 4];
      Ws[vv][k4 * 4 + 0] = w4.x;
      Ws[vv][k4 * 4 + 1] = w4.y;
      Ws[vv][k4 * 4 + 2] = w4.z;
      Ws[vv][k4 * 4 + 3] = w4.w;
    }
#pragma unroll
    for (int i = 0; i < 8; ++i) {
      int e = t + i * 256;
      int k = e >> 4, b4 = e & 15;
      ushort4 hv = *(const ushort4*)&hT[(size_t)(kc + k) * 64 + b4 * 4];
      float4 fv = {h2f(hv.x), h2f(hv.y), h2f(hv.z), h2f(hv.w)};
      *(float4*)&hs[k][b4 * 4] = fv;
    }
    __syncthreads();
    for (int k = 0; k < 128; ++k) {
      const float wv = Ws[v][k];
      const float4 ha = *(const float4*)&hs[k][bbase];
      const float4 hb = *(const float4*)&hs[k][bbase + 4];
      acc[0] = fmaf(wv, ha.x, acc[0]);
      acc[1] = fmaf(wv, ha.y, acc[1]);
      acc[2] = fmaf(wv, ha.z, acc[2]);
      acc[3] = fmaf(wv, ha.w, acc[3]);
      acc[4] = fmaf(wv, hb.x, acc[4]);
      acc[5] = fmaf(wv, hb.y, acc[5]);
      acc[6] = fmaf(wv, hb.z, acc[6]);
      acc[7] = fmaf(wv, hb.w, acc[7]);
    }
    __syncthreads();
  }
  const float bias = bfc[v0 + v];
#pragma unroll
  for (int i = 0; i < 8; ++i)
    out[(size_t)(bbase + i) * VOCAB + v0 + v] = acc[i] + bias;
}

// =====================================================================
extern "C" void kernel_launch(void* const* d_in, const int* in_sizes, int n_in,
                              void* d_out, int out_size, void* d_ws,
                              size_t ws_size, hipStream_t stream) {
  const int* x = (const int*)d_in[0];
  const float* emb = (const float*)d_in[1];
  const float* Wih = (const float*)d_in[2];
  const float* Whh = (const float*)d_in[3];
  const float* bih = (const float*)d_in[4];
  const float* bhh = (const float*)d_in[5];
  const float* Wfc = (const float*)d_in[6];
  const float* bfc = (const float*)d_in[7];
  float* out = (float*)d_out;

  char* ws = (char*)d_ws;
  const size_t XPB = (size_t)SEQ * 64 * G4H * sizeof(u16);  // 256 MiB
  u16* xp = (u16*)ws;
  u16* hA = (u16*)(ws + XPB);
  u16* hB = (u16*)(ws + XPB + 131072);
  u16* hT = (u16*)(ws + XPB + 262144);
  unsigned* flags = (unsigned*)(ws + XPB + 393216);  // 64 x 128B

  hipMemsetAsync(hA, 0, 131072, stream);
  hipMemsetAsync(flags, 0, LBLK * 128, stream);

  phaseA<<<dim3(32, 256), 256, 0, stream>>>(x, emb, Wih, bih, bhh, xp);

  {
    const u16* xp_c = xp;
    const float* Whh_c = Whh;
    void* args[] = {(void*)&xp_c, (void*)&Whh_c, (void*)&hA, (void*)&hB,
                    (void*)&hT,   (void*)&flags};
    hipLaunchCooperativeKernel((const void*)lstm_steps, dim3(LBLK), dim3(512),
                               args, 0, stream);
  }

  phaseC<<<1000, 256, 0, stream>>>(hT, Wfc, bfc, out);
}

// Round 17
// 3805.913 us; speedup vs baseline: 1.0138x; 1.0138x over previous
//
#include <hip/hip_runtime.h>

typedef unsigned short u16;
typedef unsigned int u32;
typedef float f32x4 __attribute__((ext_vector_type(4)));
typedef _Float16 f16x8 __attribute__((ext_vector_type(8)));

#define VOCAB 32000
#define EMBED 512
#define HIDDEN 1024
#define BATCH 64
#define SEQ 512
#define G4H 4096
#define LBLK 64  // lstm persistent blocks

// ---------- fp16 helpers ----------
static __device__ __forceinline__ float h2f(u16 v) {
  _Float16 h;
  __builtin_memcpy(&h, &v, 2);
  return (float)h;
}
static __device__ __forceinline__ u16 f2h(float f) {
  _Float16 h = (_Float16)f;
  u16 v;
  __builtin_memcpy(&v, &h, 2);
  return v;
}
static __device__ __forceinline__ u32 pk2h(float a, float b) {
  return (u32)f2h(a) | ((u32)f2h(b) << 16);
}
static __device__ __forceinline__ float sigmoidf_(float x) {
  return 1.f / (1.f + __expf(-x));
}
static __device__ __forceinline__ float tanhf_(float x) {
  return 1.f - 2.f / (__expf(2.f * x) + 1.f);
}
static __device__ __forceinline__ f16x8 cvt8(const float* p) {
  float4 a = *(const float4*)p, b = *(const float4*)(p + 4);
  f16x8 v;
  v[0] = (_Float16)a.x; v[1] = (_Float16)a.y;
  v[2] = (_Float16)a.z; v[3] = (_Float16)a.w;
  v[4] = (_Float16)b.x; v[5] = (_Float16)b.y;
  v[6] = (_Float16)b.z; v[7] = (_Float16)b.w;
  return v;
}
static __device__ __forceinline__ f16x8 cvt8r(float4 a, float4 b) {
  f16x8 v;
  v[0] = (_Float16)a.x; v[1] = (_Float16)a.y;
  v[2] = (_Float16)a.z; v[3] = (_Float16)a.w;
  v[4] = (_Float16)b.x; v[5] = (_Float16)b.y;
  v[6] = (_Float16)b.z; v[7] = (_Float16)b.w;
  return v;
}

// coherent (cross-XCD) 16B load: bypasses L1/L2, served by IF/L3
#define GLOADC(dst, addr)                                  \
  asm volatile("global_load_dwordx4 %0, %1, off sc0 sc1"  \
               : "=v"(dst)                                 \
               : "v"(addr)                                 \
               : "memory")

// =====================================================================
// Phase A: xp = emb_table[x] @ W_ih^T + b_ih + b_hh, fp16 MFMA GEMM.
// Output layout [t][b][u*4+c]. (R10 version — verified 4x)
// =====================================================================
__global__ __launch_bounds__(256, 2) void phaseA(
    const int* __restrict__ x, const float* __restrict__ emb,
    const float* __restrict__ Wih, const float* __restrict__ bih,
    const float* __restrict__ bhh, u16* __restrict__ xp) {
  __shared__ __align__(16) _Float16 Al[128 * 32];
  __shared__ __align__(16) _Float16 Bl[128 * 32];
  const int t = threadIdx.x;
  const int bx = blockIdx.x;  // n-tile 0..31
  const int by = blockIdx.y;  // m-tile 0..255
  const int m0 = by * 128;
  const int u0 = bx * 32;

  const int r0 = x[m0 + (t >> 2)];
  const int r1 = x[m0 + 64 + (t >> 2)];
  const int nl0 = t >> 2, nl1 = 64 + (t >> 2);
  const int wrow0 = u0 + (nl0 >> 2) + (nl0 & 3) * 1024;
  const int wrow1 = u0 + (nl1 >> 2) + (nl1 & 3) * 1024;
  const int kq = t & 3;
  const float* pA0 = emb + (size_t)r0 * EMBED + kq * 8;
  const float* pA1 = emb + (size_t)r1 * EMBED + kq * 8;
  const float* pB0 = Wih + (size_t)wrow0 * EMBED + kq * 8;
  const float* pB1 = Wih + (size_t)wrow1 * EMBED + kq * 8;

  const int wid = t >> 6, l = t & 63;
  const int wr = wid >> 1, wc = wid & 1;
  const int lm = l & 15, lk = l >> 4;

  f32x4 acc[4][4];
#pragma unroll
  for (int i = 0; i < 4; ++i)
#pragma unroll
    for (int j = 0; j < 4; ++j) acc[i][j] = (f32x4){0.f, 0.f, 0.f, 0.f};

  // preload K-chunk 0 into named registers
  float4 ra0a = *(const float4*)(pA0), ra0b = *(const float4*)(pA0 + 4);
  float4 ra1a = *(const float4*)(pA1), ra1b = *(const float4*)(pA1 + 4);
  float4 rb0a = *(const float4*)(pB0), rb0b = *(const float4*)(pB0 + 4);
  float4 rb1a = *(const float4*)(pB1), rb1b = *(const float4*)(pB1 + 4);

  for (int k0 = 0; k0 < EMBED; k0 += 32) {
    *(f16x8*)(Al + t * 8) = cvt8r(ra0a, ra0b);
    *(f16x8*)(Al + (t + 256) * 8) = cvt8r(ra1a, ra1b);
    *(f16x8*)(Bl + t * 8) = cvt8r(rb0a, rb0b);
    *(f16x8*)(Bl + (t + 256) * 8) = cvt8r(rb1a, rb1b);
    __syncthreads();
    if (k0 + 32 < EMBED) {  // issue next chunk early; retires during MFMAs
      const int kn = k0 + 32;
      ra0a = *(const float4*)(pA0 + kn); ra0b = *(const float4*)(pA0 + kn + 4);
      ra1a = *(const float4*)(pA1 + kn); ra1b = *(const float4*)(pA1 + kn + 4);
      rb0a = *(const float4*)(pB0 + kn); rb0b = *(const float4*)(pB0 + kn + 4);
      rb1a = *(const float4*)(pB1 + kn); rb1b = *(const float4*)(pB1 + kn + 4);
    }
    f16x8 af[4], bf[4];
#pragma unroll
    for (int mt = 0; mt < 4; ++mt)
      af[mt] = *(const f16x8*)(Al + (wr * 64 + mt * 16 + lm) * 32 + lk * 8);
#pragma unroll
    for (int nt = 0; nt < 4; ++nt)
      bf[nt] = *(const f16x8*)(Bl + (wc * 64 + nt * 16 + lm) * 32 + lk * 8);
#pragma unroll
    for (int mt = 0; mt < 4; ++mt)
#pragma unroll
      for (int nt = 0; nt < 4; ++nt)
        acc[mt][nt] = __builtin_amdgcn_mfma_f32_16x16x32_f16(
            af[mt], bf[nt], acc[mt][nt], 0, 0, 0);
    __syncthreads();
  }

#pragma unroll
  for (int nt = 0; nt < 4; ++nt) {
    const int nloc = wc * 64 + nt * 16 + lm;
    const int grow = u0 + (nloc >> 2) + (nloc & 3) * 1024;
    const float bsum = bih[grow] + bhh[grow];
#pragma unroll
    for (int mt = 0; mt < 4; ++mt)
#pragma unroll
      for (int r = 0; r < 4; ++r) {
        const int m = m0 + wr * 64 + mt * 16 + lk * 4 + r;
        const int bb = m >> 9, tt = m & 511;
        xp[((size_t)tt * 64 + bb) * G4H + bx * 128 + nloc] =
            f2h(acc[mt][nt][r] + bsum);
      }
  }
}

// =====================================================================
// Persistent LSTM, 64 blocks x 512 thr (8 waves), cooperative.
// EXACT R15 (best verified: lstm 3450us, total 3807us, absmax 4.88e-4).
// R16's b32-split write swizzle REVERTED (regressed: conflicts 2x).
// ps XOR-swizzle (lk&1)<<6 on write+read: gate-math reads 2-way free.
// =====================================================================
__global__ __launch_bounds__(512, 2) void lstm_steps(
    const u16* __restrict__ xp, const float* __restrict__ Whh,
    u16* __restrict__ hA, u16* __restrict__ hB, u16* __restrict__ hT,
    unsigned* __restrict__ flags) {
  __shared__ __align__(16) char psb[65536];
  const int t = threadIdx.x;
  const int blk = blockIdx.x;
  const int kw = t >> 6;  // wave id = K-slice
  const int l = t & 63;
  const int lm = l & 15, lk = l >> 4;

  // ---- W_hh A-frags (fp16), once: wf[rt=gate][kf] ----
  f16x8 wf[4][4];
#pragma unroll
  for (int rt = 0; rt < 4; ++rt)
#pragma unroll
    for (int kf = 0; kf < 4; ++kf)
      wf[rt][kf] = cvt8(Whh + (size_t)(rt * HIDDEN + blk * 16 + lm) * HIDDEN +
                        kw * 128 + kf * 32 + lk * 8);

  const int gb = t >> 3, gup = t & 7;  // gate-math role: batch, unit-pair
  // write base: intra-slot byte = l*8, XOR-swizzled by (lk&1)<<6
  const unsigned wbase =
      (unsigned)(kw * 8192 + ((l * 8) ^ ((lk & 1) << 6)));
  // read offset: same swizzle with lk = gup>>1, lm = gb&15, d = gup&1
  const unsigned roff =
      (unsigned)((gb >> 4) * 512 +
                 (((gup >> 1) * 128 + (gb & 15) * 8 + (gup & 1) * 4) ^
                  (((gup >> 1) & 1) << 6)));
  const size_t xpofs = (size_t)gb * G4H + (size_t)blk * 64 + gup * 8;
  const int pfl = (kw * 8 + (l & 7)) * 32;  // producer-subset poll index
  float c0 = 0.f, c1 = 0.f;

  // prefetch xv for s=0 (retired by first bt-loop's waits)
  f16x8 xv;
  GLOADC(xv, xp + xpofs);

  for (int s = 0; s < SEQ; ++s) {
    const u16* hp = (s & 1) ? hB : hA;
    u16* hn = (s & 1) ? hA : hB;

    // 16 h loads (producers for this wave's k-slice already flagged)
    f16x8 bv[4][4];
#pragma unroll
    for (int bt = 0; bt < 4; ++bt)
#pragma unroll
      for (int kf = 0; kf < 4; ++kf)
        GLOADC(bv[bt][kf], hp + (size_t)(bt * 16 + lm) * HIDDEN + kw * 128 +
                               kf * 32 + lk * 8);

    f32x4 acc[4][4];
#pragma unroll
    for (int i = 0; i < 4; ++i)
#pragma unroll
      for (int j = 0; j < 4; ++j) acc[i][j] = (f32x4){0.f, 0.f, 0.f, 0.f};

#pragma unroll
    for (int bt = 0; bt < 4; ++bt) {
      if (bt == 0) asm volatile("s_waitcnt vmcnt(12)" ::: "memory");
      else if (bt == 1) asm volatile("s_waitcnt vmcnt(8)" ::: "memory");
      else if (bt == 2) asm volatile("s_waitcnt vmcnt(4)" ::: "memory");
      else asm volatile("s_waitcnt vmcnt(0)" ::: "memory");
      __builtin_amdgcn_sched_barrier(0);
#pragma unroll
      for (int rt = 0; rt < 4; ++rt)
#pragma unroll
        for (int kf = 0; kf < 4; ++kf)
          acc[rt][bt] = __builtin_amdgcn_mfma_f32_16x16x32_f16(
              wf[rt][kf], bv[bt][kf], acc[rt][bt], 0, 0, 0);
    }

    // ps writes: 16 x ds_write_b64, swizzled (2-way banks = free)
#pragma unroll
    for (int rt = 0; rt < 4; ++rt)
#pragma unroll
      for (int bt = 0; bt < 4; ++bt) {
        uint2 v;
        v.x = pk2h(acc[rt][bt][0], acc[rt][bt][1]);
        v.y = pk2h(acc[rt][bt][2], acc[rt][bt][3]);
        *(uint2*)(psb + wbase + (rt * 4 + bt) * 512) = v;
      }
    __syncthreads();  // sync1: ps writes visible; all waves converged

    // ---- gate math: thread (gb, gup) -> units gup*2, gup*2+1 ----
    float s0[4], s1[4];
#pragma unroll
    for (int c = 0; c < 4; ++c) {
      s0[c] = (float)xv[c];
      s1[c] = (float)xv[4 + c];
    }
#pragma unroll
    for (int c = 0; c < 4; ++c)
#pragma unroll
      for (int k8 = 0; k8 < 8; ++k8) {
        const u32 pv = *(const u32*)(psb + k8 * 8192 + c * 2048 + roff);
        s0[c] += h2f((u16)(pv & 0xffffu));
        s1[c] += h2f((u16)(pv >> 16));
      }
    float go0, go1;
    {
      const float ig = sigmoidf_(s0[0]), fg = sigmoidf_(s0[1]);
      const float gv = tanhf_(s0[2]), og = sigmoidf_(s0[3]);
      c0 = fg * c0 + ig * gv;
      go0 = og * tanhf_(c0);
    }
    {
      const float ig = sigmoidf_(s1[0]), fg = sigmoidf_(s1[1]);
      const float gv = tanhf_(s1[2]), og = sigmoidf_(s1[3]);
      c1 = fg * c1 + ig * gv;
      go1 = og * tanhf_(c1);
    }

    if (s == SEQ - 1) {
      // final: write transposed hT[k][b] directly for phaseC
      hT[(size_t)(blk * 16 + gup * 2) * 64 + gb] = f2h(go0);
      hT[(size_t)(blk * 16 + gup * 2 + 1) * 64 + gb] = f2h(go1);
      break;
    }

    const unsigned hpack = (unsigned)f2h(go0) | ((unsigned)f2h(go1) << 16);
    __hip_atomic_store(
        (unsigned*)(hn + (size_t)gb * HIDDEN + blk * 16 + gup * 2), hpack,
        __ATOMIC_RELAXED, __HIP_MEMORY_SCOPE_AGENT);

    // prefetch next step's xp slice (gate math above already consumed xv);
    // issued AFTER the h store so vmcnt(1) drains the store, not this load
    GLOADC(xv, xp + (size_t)(s + 1) * (64 * G4H) + xpofs);
    asm volatile("s_waitcnt vmcnt(1)" ::: "memory");  // drain h store only
    __syncthreads();  // sync2: all waves' h stores drained; ps reads done
    if (t == 0)
      __hip_atomic_store(flags + blk * 32, (unsigned)(s + 1), __ATOMIC_RELAXED,
                         __HIP_MEMORY_SCOPE_AGENT);
    // all-wave producer-subset poll: wave kw waits on blocks kw*8..kw*8+7
    {
      const unsigned tgt = (unsigned)(s + 1);
      while (true) {
        unsigned v = __hip_atomic_load(flags + pfl, __ATOMIC_RELAXED,
                                       __HIP_MEMORY_SCOPE_AGENT);
        if (__all((int)(v >= tgt))) break;
        __builtin_amdgcn_s_sleep(1);
      }
    }
  }
}

// =====================================================================
// Phase C: out[b][v] = sum_k hT[k][b] * W_fc[v][k] + b_fc[v]
// (exact R15 version)
// =====================================================================
__global__ __launch_bounds__(256) void phaseC(
    const u16* __restrict__ hT, const float* __restrict__ Wfc,
    const float* __restrict__ bfc, float* __restrict__ out) {
  __shared__ float Ws[32][129];
  __shared__ __align__(16) float hs[128][68];
  const int t = threadIdx.x;
  const int v0 = blockIdx.x * 32;
  const int lane = t & 63;
  const int w = t >> 6;
  const int v = lane & 31;
  const int bbase = ((w << 1) | (lane >> 5)) << 3;
  float acc[8] = {0.f, 0.f, 0.f, 0.f, 0.f, 0.f, 0.f, 0.f};

  for (int kc = 0; kc < HIDDEN; kc += 128) {
#pragma unroll
    for (int i = 0; i < 16; ++i) {
      int e = t + i * 256;
      Ws[e >> 7][e & 127] =
          Wfc[(size_t)(v0 + (e >> 7)) * HIDDEN + kc + (e & 127)];
    }
#pragma unroll
    for (int i = 0; i < 8; ++i) {
      int e = t + i * 256;
      int k = e >> 4, b4 = e & 15;
      ushort4 hv = *(const ushort4*)&hT[(size_t)(kc + k) * 64 + b4 * 4];
      float4 fv = {h2f(hv.x), h2f(hv.y), h2f(hv.z), h2f(hv.w)};
      *(float4*)&hs[k][b4 * 4] = fv;
    }
    __syncthreads();
    for (int k = 0; k < 128; ++k) {
      const float wv = Ws[v][k];
      const float4 ha = *(const float4*)&hs[k][bbase];
      const float4 hb = *(const float4*)&hs[k][bbase + 4];
      acc[0] = fmaf(wv, ha.x, acc[0]);
      acc[1] = fmaf(wv, ha.y, acc[1]);
      acc[2] = fmaf(wv, ha.z, acc[2]);
      acc[3] = fmaf(wv, ha.w, acc[3]);
      acc[4] = fmaf(wv, hb.x, acc[4]);
      acc[5] = fmaf(wv, hb.y, acc[5]);
      acc[6] = fmaf(wv, hb.z, acc[6]);
      acc[7] = fmaf(wv, hb.w, acc[7]);
    }
    __syncthreads();
  }
  const float bias = bfc[v0 + v];
#pragma unroll
  for (int i = 0; i < 8; ++i)
    out[(size_t)(bbase + i) * VOCAB + v0 + v] = acc[i] + bias;
}

// =====================================================================
extern "C" void kernel_launch(void* const* d_in, const int* in_sizes, int n_in,
                              void* d_out, int out_size, void* d_ws,
                              size_t ws_size, hipStream_t stream) {
  const int* x = (const int*)d_in[0];
  const float* emb = (const float*)d_in[1];
  const float* Wih = (const float*)d_in[2];
  const float* Whh = (const float*)d_in[3];
  const float* bih = (const float*)d_in[4];
  const float* bhh = (const float*)d_in[5];
  const float* Wfc = (const float*)d_in[6];
  const float* bfc = (const float*)d_in[7];
  float* out = (float*)d_out;

  char* ws = (char*)d_ws;
  const size_t XPB = (size_t)SEQ * 64 * G4H * sizeof(u16);  // 256 MiB
  u16* xp = (u16*)ws;
  u16* hA = (u16*)(ws + XPB);
  u16* hB = (u16*)(ws + XPB + 131072);
  u16* hT = (u16*)(ws + XPB + 262144);
  unsigned* flags = (unsigned*)(ws + XPB + 393216);  // 64 x 128B

  hipMemsetAsync(hA, 0, 131072, stream);
  hipMemsetAsync(flags, 0, LBLK * 128, stream);

  phaseA<<<dim3(32, 256), 256, 0, stream>>>(x, emb, Wih, bih, bhh, xp);

  {
    const u16* xp_c = xp;
    const float* Whh_c = Whh;
    void* args[] = {(void*)&xp_c, (void*)&Whh_c, (void*)&hA, (void*)&hB,
                    (void*)&hT,   (void*)&flags};
    hipLaunchCooperativeKernel((const void*)lstm_steps, dim3(LBLK), dim3(512),
                               args, 0, stream);
  }

  phaseC<<<1000, 256, 0, stream>>>(hT, Wfc, bfc, out);
}